// Round 13
// baseline (359.959 us; speedup 1.0000x reference)
//
#include <hip/hip_runtime.h>
#include <cstdint>
#include <cstddef>

typedef unsigned short u16;
typedef float f32x4 __attribute__((ext_vector_type(4)));
typedef short s16x8 __attribute__((ext_vector_type(8)));
typedef unsigned short u16x4 __attribute__((ext_vector_type(4)));
typedef __bf16 bf16x8 __attribute__((ext_vector_type(8)));

#define DEV static __device__ __forceinline__

DEV u16 f2bf(float f) {
  uint32_t x = __float_as_uint(f);
  return (u16)((x + 0x7fffu + ((x >> 16) & 1u)) >> 16);  // RNE
}

DEV f32x4 mfma16(bf16x8 a, bf16x8 b, f32x4 c) {
  return __builtin_amdgcn_mfma_f32_16x16x32_bf16(a, b, c, 0, 0, 0);
}

DEV void mfma_bf16_asm(f32x4& acc, s16x8 a, s16x8 b) {
  asm volatile("v_mfma_f32_16x16x32_bf16 %0, %1, %2, %0" : "+v"(acc) : "v"(a), "v"(b));
}

DEV uint32_t pkbf(float lo, float hi) {
  uint32_t r;
  asm("v_cvt_pk_bf16_f32 %0, %1, %2" : "=v"(r) : "v"(lo), "v"(hi));
  return r;
}

// ---------------- mega prep: folds + casts + x_cls copy + patch norm ----------------
__global__ __launch_bounds__(256) void k_prep(
    const float* __restrict__ x_cls, const float* __restrict__ x_patch,
    const float* __restrict__ k_w, const float* __restrict__ v_w,
    const float* __restrict__ q_w, const float* __restrict__ proj_w,
    const float* __restrict__ fc1_w, const float* __restrict__ fc2_w,
    const float* __restrict__ ln1_w, const float* __restrict__ ln1_b,
    const float* __restrict__ ln2_w, const float* __restrict__ ln2_b,
    const float* __restrict__ fc1_b,
    u16* __restrict__ kvp, u16* __restrict__ qp, u16* __restrict__ pjp,
    u16* __restrict__ f1p, u16* __restrict__ f2p,
    float* __restrict__ bias_kv, float* __restrict__ bias_q, float* __restrict__ bias_f1,
    float* __restrict__ xc, u16* __restrict__ nxp) {
  const int jb = blockIdx.x;
  const int lane = threadIdx.x & 63;
  if (jb >= 2736) {
    int wv = (jb - 2736) * 4 + (threadIdx.x >> 6);
    if (wv >= 129600) return;
    float4 v = ((const float4*)(x_patch + (size_t)wv * 256))[lane];
    float s = v.x + v.y + v.z + v.w;
    float q = v.x * v.x + v.y * v.y + v.z * v.z + v.w * v.w;
#pragma unroll
    for (int m = 1; m < 64; m <<= 1) {
      s += __shfl_xor(s, m, 64);
      q += __shfl_xor(q, m, 64);
    }
    float mean = s * (1.f / 256.f);
    float var = q * (1.f / 256.f) - mean * mean;
    float rstd = rsqrtf(var + 1e-5f);
    u16x4 o;
    o[0] = f2bf((v.x - mean) * rstd);
    o[1] = f2bf((v.y - mean) * rstd);
    o[2] = f2bf((v.z - mean) * rstd);
    o[3] = f2bf((v.w - mean) * rstd);
    ((u16x4*)(nxp + (size_t)wv * 256))[lane] = o;
    return;
  }
  if (jb >= 1536) {
    int i = (jb - 1536) * 256 + threadIdx.x;
    ((float4*)xc)[i] = ((const float4*)x_cls)[i];
    return;
  }
  const int layer = jb >= 768 ? 1 : 0;
  const int j = jb - layer * 768;
  const float* W;
  const float* lw = ln1_w + layer * 256;
  const float* lb = ln1_b + layer * 256;
  const float* b0 = nullptr;
  u16* Wout;
  float* bout = nullptr;
  int rowoff;
  if (j < 64)       { W = k_w + layer * 65536;    Wout = kvp + layer * 131072;         bout = bias_kv + layer * 512;       rowoff = j * 4; }
  else if (j < 128) { W = v_w + layer * 65536;    Wout = kvp + layer * 131072 + 65536; bout = bias_kv + layer * 512 + 256; rowoff = (j - 64) * 4; }
  else if (j < 192) { W = q_w + layer * 65536;    Wout = qp + layer * 65536;           bout = bias_q + layer * 256;        rowoff = (j - 128) * 4; }
  else if (j < 448) { W = fc1_w + layer * 262144; lw = ln2_w + layer * 256; lb = ln2_b + layer * 256; b0 = fc1_b + layer * 1024;
                      Wout = f1p + layer * 262144; bout = bias_f1 + layer * 1024;      rowoff = (j - 192) * 4; }
  else if (j < 512) { W = proj_w + layer * 65536; lw = nullptr;                        Wout = pjp + layer * 65536;         rowoff = (j - 448) * 4; }
  else              { W = fc2_w + layer * 262144; lw = nullptr;                        Wout = f2p + layer * 262144;        rowoff = (j - 512) * 4; }
  const int wv = rowoff + (threadIdx.x >> 6);
  float4 w4 = ((const float4*)(W + (size_t)wv * 256))[lane];
  u16x4 o;
  if (lw) {
    float4 s4 = ((const float4*)lw)[lane];
    o[0] = f2bf(w4.x * s4.x); o[1] = f2bf(w4.y * s4.y);
    o[2] = f2bf(w4.z * s4.z); o[3] = f2bf(w4.w * s4.w);
  } else {
    o[0] = f2bf(w4.x); o[1] = f2bf(w4.y); o[2] = f2bf(w4.z); o[3] = f2bf(w4.w);
  }
  ((u16x4*)(Wout + (size_t)wv * 256))[lane] = o;
  if (bout) {
    float4 t4 = ((const float4*)lb)[lane];
    float d = w4.x * t4.x + w4.y * t4.y + w4.z * t4.z + w4.w * t4.w;
#pragma unroll
    for (int m = 1; m < 64; m <<= 1) d += __shfl_xor(d, m, 64);
    if (lane == 0) bout[wv] = (b0 ? b0[wv] : 0.f) + d;
  }
}

// ---------------- Pure normalize (affine folded into weights) ----------
__global__ __launch_bounds__(256) void k_norm(const float* __restrict__ src,
                                              u16* __restrict__ out, int ntok) {
  int wv = blockIdx.x * 4 + (threadIdx.x >> 6), lane = threadIdx.x & 63;
  if (wv >= ntok) return;
  float4 v = ((const float4*)(src + (size_t)wv * 256))[lane];
  float s = v.x + v.y + v.z + v.w;
  float q = v.x * v.x + v.y * v.y + v.z * v.z + v.w * v.w;
#pragma unroll
  for (int m = 1; m < 64; m <<= 1) {
    s += __shfl_xor(s, m, 64);
    q += __shfl_xor(q, m, 64);
  }
  float mean = s * (1.f / 256.f);
  float var = q * (1.f / 256.f) - mean * mean;
  float rstd = rsqrtf(var + 1e-5f);
  u16x4 o;
  o[0] = f2bf((v.x - mean) * rstd);
  o[1] = f2bf((v.y - mean) * rstd);
  o[2] = f2bf((v.z - mean) * rstd);
  o[3] = f2bf((v.w - mean) * rstd);
  ((u16x4*)(out + (size_t)wv * 256))[lane] = o;
}

// ---------------- small-M MFMA GEMM: 64x128 tile, BK=64 (R8-proven) ----------------
__global__ __launch_bounds__(256) void k_gemm6(const u16* __restrict__ A,
                                               const u16* __restrict__ Bw,
                                               int N, int K, int mode,
                                               int lognby, float scale,
                                               const float* __restrict__ bias,
                                               const float* __restrict__ gamma,
                                               u16* __restrict__ obf,
                                               float* __restrict__ of32) {
  __shared__ __align__(16) char smA[8192];
  __shared__ __align__(16) char smB[16384];
  const int tid = threadIdx.x, lane = tid & 63, wid = tid >> 6;
  const int wm = wid >> 1, wn = wid & 1;
  const int bid = blockIdx.x;
  const int by = bid & ((1 << lognby) - 1), bx = bid >> lognby;
  const int m0 = bx * 64, n0 = by * 128;
  const int g = lane >> 4, l15 = lane & 15;

  f32x4 acc[2][4] = {};

  for (int k0 = 0; k0 < K; k0 += 64) {
#pragma unroll
    for (int c = 0; c < 2; c++) {
      int ee = tid + 256 * c;
      int row = ee >> 3, sl = ee & 7;
      s16x8 av = *(const s16x8*)(A + (size_t)(m0 + row) * K + k0 + sl * 8);
      *(s16x8*)(smA + row * 128 + ((sl * 16) ^ ((row & 7) << 4))) = av;
    }
#pragma unroll
    for (int c = 0; c < 4; c++) {
      int ee = tid + 256 * c;
      int row = ee >> 3, sl = ee & 7;
      s16x8 bv = *(const s16x8*)(Bw + (size_t)(n0 + row) * K + k0 + sl * 8);
      *(s16x8*)(smB + row * 128 + ((sl * 16) ^ ((row & 7) << 4))) = bv;
    }
    __syncthreads();
    s16x8 af[2][2], bfr[4][2];
#pragma unroll
    for (int s = 0; s < 2; s++) {
#pragma unroll
      for (int i = 0; i < 2; i++) {
        int r = wm * 32 + i * 16 + l15;
        af[i][s] = *(const s16x8*)(smA + r * 128 + (((s * 4 + g) * 16) ^ ((r & 7) << 4)));
      }
#pragma unroll
      for (int jj = 0; jj < 4; jj++) {
        int n = wn * 64 + jj * 16 + l15;
        bfr[jj][s] = *(const s16x8*)(smB + n * 128 + (((s * 4 + g) * 16) ^ ((n & 7) << 4)));
      }
    }
#pragma unroll
    for (int s = 0; s < 2; s++)
#pragma unroll
      for (int i = 0; i < 2; i++)
#pragma unroll
        for (int jj = 0; jj < 4; jj++)
          mfma_bf16_asm(acc[i][jj], af[i][s], bfr[jj][s]);
    __syncthreads();
  }
  asm volatile("s_nop 7\n\ts_nop 7" ::: "memory");

#pragma unroll
  for (int i = 0; i < 2; i++) {
#pragma unroll
    for (int jj = 0; jj < 4; jj++) {
      int gmBase = m0 + wm * 32 + i * 16 + g * 4;
      int gn = n0 + wn * 64 + jj * 16 + l15;
      float bs = bias[gn];
#pragma unroll
      for (int r = 0; r < 4; r++) {
        int gm = gmBase + r;
        float v = acc[i][jj][r] + bs;
        if (mode == 1) {
          obf[(size_t)gm * N + gn] = f2bf(v * scale);
        } else if (mode == 2) {
          of32[(size_t)gm * N + gn] += gamma[gn] * v;
        } else {
          obf[(size_t)gm * N + gn] = f2bf(0.5f * v * (1.f + erff(v * 0.70710678118654752f)));
        }
      }
    }
  }
}

// ---------------- Fused K/V-projection + flash attention, token-split x2, TILE-PAIRED ---
// grid 1024: b = bid&63, h = (bid>>6)&7, half = bid>>9. Fixed-max softmax (R10-proven).
// Pairing: one kstep loop loads each weight fragment ONCE and feeds both tiles'
// projection MFMAs -> WL ds_read_b128 traffic halves (the DS pipe was ~50% busy).
__global__ __launch_bounds__(256, 2) void k_fattn(const u16* __restrict__ qb,
                                                  const u16* __restrict__ uncls,
                                                  const u16* __restrict__ nxp,
                                                  const u16* __restrict__ wkv,
                                                  const float* __restrict__ bias_kv,
                                                  float* __restrict__ pO,
                                                  float* __restrict__ pml) {
  __shared__ __align__(16) char arena[50176];
  __shared__ float mlS[4][80];
  const int bid = blockIdx.x;
  const int b = bid & 63, h = (bid >> 6) & 7, half = bid >> 9;
  const int tid = threadIdx.x, lane = tid & 63, w = tid >> 6;
  const int l15 = lane & 15, g = lane >> 4;
  const int tbase = half * 33;

  u16* WL = (u16*)arena;                      // [64][256] u16, row-xor swizzle
  char* wb = arena + 32768 + w * 4352;
  uint32_t* KL = (uint32_t*)wb;               // [32 tok][16 u32]
  uint32_t* PB = (uint32_t*)wb;               // overlay (KL consumed to regs before PB use)
  u16* VL = (u16*)(wb + 2048);                // [32 tok][36 d] u16 (padded rows)

  // ---- stage head weights (Wk rows 0..31, Wv rows 32..63) ----
  for (int it = tid; it < 2048; it += 256) {
    int row = it >> 5, c16 = it & 31;
    int srcRow = (row < 32) ? (h * 32 + row) : (256 + h * 32 + (row - 32));
    s16x8 w8 = *(const s16x8*)(wkv + (size_t)srcRow * 256 + c16 * 8);
    *(s16x8*)(WL + row * 256 + (((c16 * 16) ^ ((row & 7) << 4)) >> 1)) = w8;
  }

  float bk[2][4], bvb[2][4];
#pragma unroll
  for (int s2 = 0; s2 < 2; s2++)
#pragma unroll
    for (int r = 0; r < 4; r++) {
      bk[s2][r] = bias_kv[h * 32 + s2 * 16 + 4 * g + r];
      bvb[s2][r] = bias_kv[256 + h * 32 + s2 * 16 + 4 * g + r];
    }

  bf16x8 bq[5];
#pragma unroll
  for (int qt = 0; qt < 5; qt++) {
    int q = qt * 16 + l15; if (q > 74) q = 74;
    s16x8 qv = *(const s16x8*)(qb + (size_t)(b * 75 + q) * 256 + h * 32 + g * 8);
    bq[qt] = __builtin_bit_cast(bf16x8, qv);
  }

  f32x4 acc[5][2] = {};
  float llc[5];
#pragma unroll
  for (int qt = 0; qt < 5; qt++) llc[qt] = 0.f;

  __syncthreads();  // weights staged

  const int xw = (l15 & 7) << 4;   // weight-row xor
  const int xk = (l15 & 3) << 2;   // KL slot xor (R7-proven)

  // attention phase for one projected tile (R10-proven body)
  auto attend = [&](f32x4 (&aK)[2][2], f32x4 (&aV)[2][2], int t0) {
#pragma unroll
    for (int s2 = 0; s2 < 2; s2++)
#pragma unroll
      for (int u = 0; u < 2; u++) {
        const int trow = u * 16 + l15;
        f32x4 kk4 = aK[s2][u];
        uint2 pk2;
        pk2.x = pkbf(kk4[0] + bk[s2][0], kk4[1] + bk[s2][1]);
        pk2.y = pkbf(kk4[2] + bk[s2][2], kk4[3] + bk[s2][3]);
        *(uint2*)&KL[trow * 16 + ((s2 * 8 + 2 * g) ^ ((trow & 3) << 2))] = pk2;
        f32x4 vv4 = aV[s2][u];
        uint2 pv2;
        pv2.x = pkbf(vv4[0] + bvb[s2][0], vv4[1] + bvb[s2][1]);
        pv2.y = pkbf(vv4[2] + bvb[s2][2], vv4[3] + bvb[s2][3]);
        *(uint2*)&VL[trow * 36 + s2 * 16 + 4 * g] = pv2;   // same addresses, b64
      }

    uint4 ka = *(const uint4*)&KL[l15 * 16 + ((4 * g) ^ xk)];
    uint4 kb = *(const uint4*)&KL[(16 + l15) * 16 + ((4 * g) ^ xk)];
    bf16x8 bA = __builtin_bit_cast(bf16x8, ka);
    bf16x8 bB = __builtin_bit_cast(bf16x8, kb);
    s16x8 v0, v1;
#pragma unroll
    for (int e = 0; e < 8; e++) {
      v0[e] = (short)VL[(8 * g + e) * 36 + l15];
      v1[e] = (short)VL[(8 * g + e) * 36 + 16 + l15];
    }
    bf16x8 bv0 = __builtin_bit_cast(bf16x8, v0);
    bf16x8 bv1 = __builtin_bit_cast(bf16x8, v1);

    const bool lastTile = (t0 == 2080);

#pragma unroll
    for (int qt = 0; qt < 5; qt++) {
      f32x4 z = {0.f, 0.f, 0.f, 0.f};
      f32x4 sA = mfma16(bA, bq[qt], z);
      f32x4 sB = mfma16(bB, bq[qt], z);
      if (lastTile && g >= 1) {   // tokens t0+16+4g+r >= 2100
        sB[0] = sB[1] = sB[2] = sB[3] = -1e30f;
      }
      f32x4 pA, pB;
#pragma unroll
      for (int r = 0; r < 4; r++) {
        pA[r] = exp2f(sA[r]);
        pB[r] = exp2f(sB[r]);
      }
      llc[qt] += pA[0] + pA[1] + pA[2] + pA[3] + pB[0] + pB[1] + pB[2] + pB[3];
      uint32_t* Pu = &PB[l15 * 20];
      Pu[2 * g]     = pkbf(pA[0], pA[1]);
      Pu[2 * g + 1] = pkbf(pA[2], pA[3]);
      Pu[8 + 2 * g]     = pkbf(pB[0], pB[1]);
      Pu[8 + 2 * g + 1] = pkbf(pB[2], pB[3]);
      uint4 pu = *(const uint4*)&PB[l15 * 20 + 4 * g];
      bf16x8 bp = __builtin_bit_cast(bf16x8, pu);
      acc[qt][0] = mfma16(bp, bv0, acc[qt][0]);
      acc[qt][1] = mfma16(bp, bv1, acc[qt][1]);
    }
  };

  for (int p = w; p < 17; p += 4) {
    const int t0a = (tbase + 2 * p) * 32;
    const bool has2 = (2 * p + 1) < 33;   // wave-uniform
    const int t0b = t0a + 32;

    int tA0 = t0a + l15;      if (tA0 > 2099) tA0 = 2099;
    int tB0 = t0a + 16 + l15; if (tB0 > 2099) tB0 = 2099;
    int tA1 = t0b + l15;      if (tA1 > 2099) tA1 = 2099;
    int tB1 = t0b + 16 + l15; if (tB1 > 2099) tB1 = 2099;
    const u16* rowA0 = (tA0 < 75) ? uncls + ((size_t)b * 75 + tA0) * 256
                                  : nxp + ((size_t)b * 2025 + (tA0 - 75)) * 256;
    const u16* rowB0 = (tB0 < 75) ? uncls + ((size_t)b * 75 + tB0) * 256
                                  : nxp + ((size_t)b * 2025 + (tB0 - 75)) * 256;
    const u16* rowA1 = (tA1 < 75) ? uncls + ((size_t)b * 75 + tA1) * 256
                                  : nxp + ((size_t)b * 2025 + (tA1 - 75)) * 256;
    const u16* rowB1 = (tB1 < 75) ? uncls + ((size_t)b * 75 + tB1) * 256
                                  : nxp + ((size_t)b * 2025 + (tB1 - 75)) * 256;

    // ---- project K,V for BOTH tiles: shared weight-fragment loads ----
    f32x4 aK0[2][2] = {}, aV0[2][2] = {}, aK1[2][2] = {}, aV1[2][2] = {};
    __builtin_amdgcn_s_setprio(1);
#pragma unroll
    for (int ks = 0; ks < 8; ks++) {
      const int cb = (ks * 64 + g * 16) ^ xw;
      bf16x8 k0 = __builtin_bit_cast(bf16x8, *(const s16x8*)(WL + l15 * 256 + (cb >> 1)));
      bf16x8 k1 = __builtin_bit_cast(bf16x8, *(const s16x8*)(WL + (16 + l15) * 256 + (cb >> 1)));
      bf16x8 w0 = __builtin_bit_cast(bf16x8, *(const s16x8*)(WL + (32 + l15) * 256 + (cb >> 1)));
      bf16x8 w1 = __builtin_bit_cast(bf16x8, *(const s16x8*)(WL + (48 + l15) * 256 + (cb >> 1)));
      bf16x8 nA0 = __builtin_bit_cast(bf16x8, *(const s16x8*)(rowA0 + ks * 32 + g * 8));
      bf16x8 nB0 = __builtin_bit_cast(bf16x8, *(const s16x8*)(rowB0 + ks * 32 + g * 8));
      aK0[0][0] = mfma16(k0, nA0, aK0[0][0]);
      aK0[0][1] = mfma16(k0, nB0, aK0[0][1]);
      aK0[1][0] = mfma16(k1, nA0, aK0[1][0]);
      aK0[1][1] = mfma16(k1, nB0, aK0[1][1]);
      aV0[0][0] = mfma16(w0, nA0, aV0[0][0]);
      aV0[0][1] = mfma16(w0, nB0, aV0[0][1]);
      aV0[1][0] = mfma16(w1, nA0, aV0[1][0]);
      aV0[1][1] = mfma16(w1, nB0, aV0[1][1]);
      if (has2) {
        bf16x8 nA1 = __builtin_bit_cast(bf16x8, *(const s16x8*)(rowA1 + ks * 32 + g * 8));
        bf16x8 nB1 = __builtin_bit_cast(bf16x8, *(const s16x8*)(rowB1 + ks * 32 + g * 8));
        aK1[0][0] = mfma16(k0, nA1, aK1[0][0]);
        aK1[0][1] = mfma16(k0, nB1, aK1[0][1]);
        aK1[1][0] = mfma16(k1, nA1, aK1[1][0]);
        aK1[1][1] = mfma16(k1, nB1, aK1[1][1]);
        aV1[0][0] = mfma16(w0, nA1, aV1[0][0]);
        aV1[0][1] = mfma16(w0, nB1, aV1[0][1]);
        aV1[1][0] = mfma16(w1, nA1, aV1[1][0]);
        aV1[1][1] = mfma16(w1, nB1, aV1[1][1]);
      }
    }
    __builtin_amdgcn_s_setprio(0);

    attend(aK0, aV0, t0a);
    if (has2) attend(aK1, aV1, t0b);
  }

  // ---- one-time denominator reduce; combine 4 wave-partials ----
#pragma unroll
  for (int qt = 0; qt < 5; qt++) {
    float t = llc[qt];
    t += __shfl_xor(t, 16, 64);
    t += __shfl_xor(t, 32, 64);
    llc[qt] = t;
  }
  __syncthreads();   // everyone done with WL/KL/VL/PB
  float* MC = (float*)arena;   // [4][2560]
#pragma unroll
  for (int qt = 0; qt < 5; qt++)
#pragma unroll
    for (int dh = 0; dh < 2; dh++)
#pragma unroll
      for (int r = 0; r < 4; r++) {
        int q = qt * 16 + 4 * g + r;
        MC[w * 2560 + q * 32 + dh * 16 + l15] = acc[qt][dh][r];
      }
  if (lane < 16) {
#pragma unroll
    for (int qt = 0; qt < 5; qt++) mlS[w][qt * 16 + l15] = llc[qt];
  }
  __syncthreads();

  if (tid < 75) {
    float L = mlS[0][tid] + mlS[1][tid] + mlS[2][tid] + mlS[3][tid];
    pml[(size_t)bid * 80 + tid] = L;
  }
  for (int idx = tid; idx < 2400; idx += 256) {
    int q = idx >> 5;
    float O = MC[q * 32 + (idx & 31)] + MC[2560 + q * 32 + (idx & 31)] +
              MC[5120 + q * 32 + (idx & 31)] + MC[7680 + q * 32 + (idx & 31)];
    pO[(size_t)bid * 2400 + idx] = O;
  }
}

// ---------------- combine the two token-halves ----------------
__global__ __launch_bounds__(256) void k_acomb(const float* __restrict__ pO,
                                               const float* __restrict__ pml,
                                               u16* __restrict__ obf) {
  const int bid = blockIdx.x;  // 0..511 = (b,h)
  const int b = bid & 63, h = bid >> 6;
  const int tid = threadIdx.x;
  for (int idx = tid; idx < 2400; idx += 256) {
    int q = idx >> 5, d = idx & 31;
    float L = pml[(size_t)bid * 80 + q] + pml[(size_t)(bid + 512) * 80 + q];
    float O = pO[(size_t)bid * 2400 + idx] + pO[(size_t)(bid + 512) * 2400 + idx];
    obf[(size_t)(b * 75 + q) * 256 + h * 32 + d] = f2bf(O / L);
  }
}

// ---------------- host ----------------
extern "C" void kernel_launch(void* const* d_in, const int* in_sizes, int n_in,
                              void* d_out, int out_size, void* d_ws, size_t ws_size,
                              hipStream_t stream) {
  const float* x_cls   = (const float*)d_in[0];
  const float* x_patch = (const float*)d_in[1];
  const float* ln1_w   = (const float*)d_in[2];
  const float* ln1_b   = (const float*)d_in[3];
  const float* q_w     = (const float*)d_in[4];
  const float* k_w     = (const float*)d_in[5];
  const float* v_w     = (const float*)d_in[6];
  const float* proj_w  = (const float*)d_in[7];
  const float* proj_b  = (const float*)d_in[8];
  const float* ln2_w   = (const float*)d_in[9];
  const float* ln2_b   = (const float*)d_in[10];
  const float* fc1_w   = (const float*)d_in[11];
  const float* fc1_b   = (const float*)d_in[12];
  const float* fc2_w   = (const float*)d_in[13];
  const float* fc2_b   = (const float*)d_in[14];
  const float* gamma1  = (const float*)d_in[15];
  const float* gamma2  = (const float*)d_in[16];
  float* xc = (float*)d_out;

  char* ws = (char*)d_ws;
  size_t off = 0;
  auto alloc = [&](size_t bytes) {
    char* p = ws + off;
    off += (bytes + 255) & ~(size_t)255;
    return p;
  };
  u16* nxp   = (u16*)alloc(129600ull * 256 * 2);
  u16* uncls = (u16*)alloc(4800ull * 256 * 2);
  u16* qb    = (u16*)alloc(4800ull * 256 * 2);
  u16* ob    = (u16*)alloc(4800ull * 256 * 2);
  u16* xn    = (u16*)alloc(4800ull * 256 * 2);
  u16* hb    = (u16*)alloc(4800ull * 1024 * 2);
  u16* qp    = (u16*)alloc(2ull * 65536 * 2);
  u16* kvp   = (u16*)alloc(2ull * 131072 * 2);
  u16* pjp   = (u16*)alloc(2ull * 65536 * 2);
  u16* f1p   = (u16*)alloc(2ull * 262144 * 2);
  u16* f2p   = (u16*)alloc(2ull * 262144 * 2);
  float* bias_kv = (float*)alloc(2ull * 512 * 4);
  float* bias_q  = (float*)alloc(2ull * 256 * 4);
  float* bias_f1 = (float*)alloc(2ull * 1024 * 4);
  float* pO  = (float*)alloc(1024ull * 2400 * 4);
  float* pml = (float*)alloc(1024ull * 80 * 4);

  k_prep<<<35136, 256, 0, stream>>>(x_cls, x_patch, k_w, v_w, q_w, proj_w, fc1_w, fc2_w,
                                    ln1_w, ln1_b, ln2_w, ln2_b, fc1_b,
                                    kvp, qp, pjp, f1p, f2p,
                                    bias_kv, bias_q, bias_f1, xc, nxp);

  const float qscale = 0.25503489f;  // 1/sqrt(32) * log2(e)
  for (int i = 0; i < 2; i++) {
    k_norm<<<1200, 256, 0, stream>>>(xc, uncls, 4800);
    k_gemm6<<<150, 256, 0, stream>>>(uncls, qp + i * 65536, 256, 256, 1, 1, qscale,
                                     bias_q + i * 256, nullptr, qb, nullptr);
    k_fattn<<<1024, 256, 0, stream>>>(qb, uncls, nxp, kvp + i * 131072,
                                      bias_kv + i * 512, pO, pml);
    k_acomb<<<512, 256, 0, stream>>>(pO, pml, ob);
    k_gemm6<<<150, 256, 0, stream>>>(ob, pjp + i * 65536, 256, 256, 2, 1, 0.f,
                                     proj_b + i * 256, gamma1 + i * 256, nullptr, xc);
    k_norm<<<1200, 256, 0, stream>>>(xc, xn, 4800);
    k_gemm6<<<600, 256, 0, stream>>>(xn, f1p + i * 262144, 1024, 256, 3, 3, 0.f,
                                     bias_f1 + i * 1024, nullptr, hb, nullptr);
    k_gemm6<<<150, 256, 0, stream>>>(hb, f2p + i * 262144, 256, 1024, 2, 1, 0.f,
                                     fc2_b + i * 256, gamma2 + i * 256, nullptr, xc);
  }
}

// Round 14
// 331.668 us; speedup vs baseline: 1.0853x; 1.0853x over previous
//
#include <hip/hip_runtime.h>
#include <cstdint>
#include <cstddef>

typedef unsigned short u16;
typedef float f32x4 __attribute__((ext_vector_type(4)));
typedef short s16x8 __attribute__((ext_vector_type(8)));
typedef unsigned short u16x4 __attribute__((ext_vector_type(4)));
typedef __bf16 bf16x8 __attribute__((ext_vector_type(8)));

#define DEV static __device__ __forceinline__

DEV u16 f2bf(float f) {
  uint32_t x = __float_as_uint(f);
  return (u16)((x + 0x7fffu + ((x >> 16) & 1u)) >> 16);  // RNE
}

DEV f32x4 mfma16(bf16x8 a, bf16x8 b, f32x4 c) {
  return __builtin_amdgcn_mfma_f32_16x16x32_bf16(a, b, c, 0, 0, 0);
}

DEV void mfma_bf16_asm(f32x4& acc, s16x8 a, s16x8 b) {
  asm volatile("v_mfma_f32_16x16x32_bf16 %0, %1, %2, %0" : "+v"(acc) : "v"(a), "v"(b));
}

DEV uint32_t pkbf(float lo, float hi) {
  uint32_t r;
  asm("v_cvt_pk_bf16_f32 %0, %1, %2" : "=v"(r) : "v"(lo), "v"(hi));
  return r;
}

// ---------------- mega prep: folds + casts + x_cls copy + patch norm ----------------
__global__ __launch_bounds__(256) void k_prep(
    const float* __restrict__ x_cls, const float* __restrict__ x_patch,
    const float* __restrict__ k_w, const float* __restrict__ v_w,
    const float* __restrict__ q_w, const float* __restrict__ proj_w,
    const float* __restrict__ fc1_w, const float* __restrict__ fc2_w,
    const float* __restrict__ ln1_w, const float* __restrict__ ln1_b,
    const float* __restrict__ ln2_w, const float* __restrict__ ln2_b,
    const float* __restrict__ fc1_b,
    u16* __restrict__ kvp, u16* __restrict__ qp, u16* __restrict__ pjp,
    u16* __restrict__ f1p, u16* __restrict__ f2p,
    float* __restrict__ bias_kv, float* __restrict__ bias_q, float* __restrict__ bias_f1,
    float* __restrict__ xc, u16* __restrict__ nxp) {
  const int jb = blockIdx.x;
  const int lane = threadIdx.x & 63;
  if (jb >= 2736) {
    int wv = (jb - 2736) * 4 + (threadIdx.x >> 6);
    if (wv >= 129600) return;
    float4 v = ((const float4*)(x_patch + (size_t)wv * 256))[lane];
    float s = v.x + v.y + v.z + v.w;
    float q = v.x * v.x + v.y * v.y + v.z * v.z + v.w * v.w;
#pragma unroll
    for (int m = 1; m < 64; m <<= 1) {
      s += __shfl_xor(s, m, 64);
      q += __shfl_xor(q, m, 64);
    }
    float mean = s * (1.f / 256.f);
    float var = q * (1.f / 256.f) - mean * mean;
    float rstd = rsqrtf(var + 1e-5f);
    u16x4 o;
    o[0] = f2bf((v.x - mean) * rstd);
    o[1] = f2bf((v.y - mean) * rstd);
    o[2] = f2bf((v.z - mean) * rstd);
    o[3] = f2bf((v.w - mean) * rstd);
    ((u16x4*)(nxp + (size_t)wv * 256))[lane] = o;
    return;
  }
  if (jb >= 1536) {
    int i = (jb - 1536) * 256 + threadIdx.x;
    ((float4*)xc)[i] = ((const float4*)x_cls)[i];
    return;
  }
  const int layer = jb >= 768 ? 1 : 0;
  const int j = jb - layer * 768;
  const float* W;
  const float* lw = ln1_w + layer * 256;
  const float* lb = ln1_b + layer * 256;
  const float* b0 = nullptr;
  u16* Wout;
  float* bout = nullptr;
  int rowoff;
  if (j < 64)       { W = k_w + layer * 65536;    Wout = kvp + layer * 131072;         bout = bias_kv + layer * 512;       rowoff = j * 4; }
  else if (j < 128) { W = v_w + layer * 65536;    Wout = kvp + layer * 131072 + 65536; bout = bias_kv + layer * 512 + 256; rowoff = (j - 64) * 4; }
  else if (j < 192) { W = q_w + layer * 65536;    Wout = qp + layer * 65536;           bout = bias_q + layer * 256;        rowoff = (j - 128) * 4; }
  else if (j < 448) { W = fc1_w + layer * 262144; lw = ln2_w + layer * 256; lb = ln2_b + layer * 256; b0 = fc1_b + layer * 1024;
                      Wout = f1p + layer * 262144; bout = bias_f1 + layer * 1024;      rowoff = (j - 192) * 4; }
  else if (j < 512) { W = proj_w + layer * 65536; lw = nullptr;                        Wout = pjp + layer * 65536;         rowoff = (j - 448) * 4; }
  else              { W = fc2_w + layer * 262144; lw = nullptr;                        Wout = f2p + layer * 262144;        rowoff = (j - 512) * 4; }
  const int wv = rowoff + (threadIdx.x >> 6);
  float4 w4 = ((const float4*)(W + (size_t)wv * 256))[lane];
  u16x4 o;
  if (lw) {
    float4 s4 = ((const float4*)lw)[lane];
    o[0] = f2bf(w4.x * s4.x); o[1] = f2bf(w4.y * s4.y);
    o[2] = f2bf(w4.z * s4.z); o[3] = f2bf(w4.w * s4.w);
  } else {
    o[0] = f2bf(w4.x); o[1] = f2bf(w4.y); o[2] = f2bf(w4.z); o[3] = f2bf(w4.w);
  }
  ((u16x4*)(Wout + (size_t)wv * 256))[lane] = o;
  if (bout) {
    float4 t4 = ((const float4*)lb)[lane];
    float d = w4.x * t4.x + w4.y * t4.y + w4.z * t4.z + w4.w * t4.w;
#pragma unroll
    for (int m = 1; m < 64; m <<= 1) d += __shfl_xor(d, m, 64);
    if (lane == 0) bout[wv] = (b0 ? b0[wv] : 0.f) + d;
  }
}

// ---------------- Pure normalize (affine folded into weights) ----------
__global__ __launch_bounds__(256) void k_norm(const float* __restrict__ src,
                                              u16* __restrict__ out, int ntok) {
  int wv = blockIdx.x * 4 + (threadIdx.x >> 6), lane = threadIdx.x & 63;
  if (wv >= ntok) return;
  float4 v = ((const float4*)(src + (size_t)wv * 256))[lane];
  float s = v.x + v.y + v.z + v.w;
  float q = v.x * v.x + v.y * v.y + v.z * v.z + v.w * v.w;
#pragma unroll
  for (int m = 1; m < 64; m <<= 1) {
    s += __shfl_xor(s, m, 64);
    q += __shfl_xor(q, m, 64);
  }
  float mean = s * (1.f / 256.f);
  float var = q * (1.f / 256.f) - mean * mean;
  float rstd = rsqrtf(var + 1e-5f);
  u16x4 o;
  o[0] = f2bf((v.x - mean) * rstd);
  o[1] = f2bf((v.y - mean) * rstd);
  o[2] = f2bf((v.z - mean) * rstd);
  o[3] = f2bf((v.w - mean) * rstd);
  ((u16x4*)(out + (size_t)wv * 256))[lane] = o;
}

// ---------------- small-M MFMA GEMM: 64x128 tile, BK=64 (R8-proven) ----------------
// modes: 1 = q store: bf16(v*scale) with PERMUTED head channel (slot = pi^-1(dd))
//        2 = of32[m*N+n] += gamma[n]*v; 3 = bf16(gelu(v))
__global__ __launch_bounds__(256) void k_gemm6(const u16* __restrict__ A,
                                               const u16* __restrict__ Bw,
                                               int N, int K, int mode,
                                               int lognby, float scale,
                                               const float* __restrict__ bias,
                                               const float* __restrict__ gamma,
                                               u16* __restrict__ obf,
                                               float* __restrict__ of32) {
  __shared__ __align__(16) char smA[8192];
  __shared__ __align__(16) char smB[16384];
  const int tid = threadIdx.x, lane = tid & 63, wid = tid >> 6;
  const int wm = wid >> 1, wn = wid & 1;
  const int bid = blockIdx.x;
  const int by = bid & ((1 << lognby) - 1), bx = bid >> lognby;
  const int m0 = bx * 64, n0 = by * 128;
  const int g = lane >> 4, l15 = lane & 15;

  f32x4 acc[2][4] = {};

  for (int k0 = 0; k0 < K; k0 += 64) {
#pragma unroll
    for (int c = 0; c < 2; c++) {
      int ee = tid + 256 * c;
      int row = ee >> 3, sl = ee & 7;
      s16x8 av = *(const s16x8*)(A + (size_t)(m0 + row) * K + k0 + sl * 8);
      *(s16x8*)(smA + row * 128 + ((sl * 16) ^ ((row & 7) << 4))) = av;
    }
#pragma unroll
    for (int c = 0; c < 4; c++) {
      int ee = tid + 256 * c;
      int row = ee >> 3, sl = ee & 7;
      s16x8 bv = *(const s16x8*)(Bw + (size_t)(n0 + row) * K + k0 + sl * 8);
      *(s16x8*)(smB + row * 128 + ((sl * 16) ^ ((row & 7) << 4))) = bv;
    }
    __syncthreads();
    s16x8 af[2][2], bfr[4][2];
#pragma unroll
    for (int s = 0; s < 2; s++) {
#pragma unroll
      for (int i = 0; i < 2; i++) {
        int r = wm * 32 + i * 16 + l15;
        af[i][s] = *(const s16x8*)(smA + r * 128 + (((s * 4 + g) * 16) ^ ((r & 7) << 4)));
      }
#pragma unroll
      for (int jj = 0; jj < 4; jj++) {
        int n = wn * 64 + jj * 16 + l15;
        bfr[jj][s] = *(const s16x8*)(smB + n * 128 + (((s * 4 + g) * 16) ^ ((n & 7) << 4)));
      }
    }
#pragma unroll
    for (int s = 0; s < 2; s++)
#pragma unroll
      for (int i = 0; i < 2; i++)
#pragma unroll
        for (int jj = 0; jj < 4; jj++)
          mfma_bf16_asm(acc[i][jj], af[i][s], bfr[jj][s]);
    __syncthreads();
  }
  asm volatile("s_nop 7\n\ts_nop 7" ::: "memory");

#pragma unroll
  for (int i = 0; i < 2; i++) {
#pragma unroll
    for (int jj = 0; jj < 4; jj++) {
      int gmBase = m0 + wm * 32 + i * 16 + g * 4;
      int gn = n0 + wn * 64 + jj * 16 + l15;
      float bs = bias[gn];
#pragma unroll
      for (int r = 0; r < 4; r++) {
        int gm = gmBase + r;
        float v = acc[i][jj][r] + bs;
        if (mode == 1) {
          // permute channel within head so attention's k-slot reads are linear:
          // slot(dd) = 8*((dd&15)>>2) + 4*(dd>>4) + (dd&3)
          int hd = gn & 31;
          int slot = 8 * ((hd & 15) >> 2) + 4 * (hd >> 4) + (hd & 3);
          obf[(size_t)gm * N + (gn & ~31) + slot] = f2bf(v * scale);
        } else if (mode == 2) {
          of32[(size_t)gm * N + gn] += gamma[gn] * v;
        } else {
          obf[(size_t)gm * N + gn] = f2bf(0.5f * v * (1.f + erff(v * 0.70710678118654752f)));
        }
      }
    }
  }
}

// ---------------- Fused K/V-projection + flash attention, token-split x2 ----------------
// R11 body (in-register K/P via k-dim permutation) with occupancy PINNED to 2 blocks/CU
// (arena padded past 160KiB/3) to isolate the R11 L2-thrash confound.
__global__ __launch_bounds__(256, 2) void k_fattn(const u16* __restrict__ qb,
                                                  const u16* __restrict__ uncls,
                                                  const u16* __restrict__ nxp,
                                                  const u16* __restrict__ wkv,
                                                  const float* __restrict__ bias_kv,
                                                  float* __restrict__ pO,
                                                  float* __restrict__ pml) {
  __shared__ __align__(16) char arena[54784];   // WL 32768 + 4xVL 2304 + PAD (caps 2 blk/CU)
  __shared__ float mlS[4][80];
  const int bid = blockIdx.x;
  const int b = bid & 63, h = (bid >> 6) & 7, half = bid >> 9;
  const int tid = threadIdx.x, lane = tid & 63, w = tid >> 6;
  const int l15 = lane & 15, g = lane >> 4;
  const int tbase = half * 33, tend = tbase + 33;

  u16* WL = (u16*)arena;                        // [64][256] u16, row-xor swizzle
  u16* VL = (u16*)(arena + 32768 + w * 2304);   // [32 slot][36 d] u16 (padded rows)

  // ---- stage head weights (Wk rows 0..31, Wv rows 32..63) ----
  for (int it = tid; it < 2048; it += 256) {
    int row = it >> 5, c16 = it & 31;
    int srcRow = (row < 32) ? (h * 32 + row) : (256 + h * 32 + (row - 32));
    s16x8 w8 = *(const s16x8*)(wkv + (size_t)srcRow * 256 + c16 * 8);
    *(s16x8*)(WL + row * 256 + (((c16 * 16) ^ ((row & 7) << 4)) >> 1)) = w8;
  }

  float bk[2][4], bvb[2][4];
#pragma unroll
  for (int s2 = 0; s2 < 2; s2++)
#pragma unroll
    for (int r = 0; r < 4; r++) {
      bk[s2][r] = bias_kv[h * 32 + s2 * 16 + 4 * g + r];
      bvb[s2][r] = bias_kv[256 + h * 32 + s2 * 16 + 4 * g + r];
    }

  bf16x8 bq[5];
#pragma unroll
  for (int qt = 0; qt < 5; qt++) {
    int q = qt * 16 + l15; if (q > 74) q = 74;
    s16x8 qv = *(const s16x8*)(qb + (size_t)(b * 75 + q) * 256 + h * 32 + g * 8);
    bq[qt] = __builtin_bit_cast(bf16x8, qv);
  }

  f32x4 acc[5][2] = {};
  float llc[5];
#pragma unroll
  for (int qt = 0; qt < 5; qt++) llc[qt] = 0.f;

  __syncthreads();  // weights staged

  const int xw = (l15 & 7) << 4;                 // weight-row xor
  const int srowA = 8 * (l15 >> 2) + (l15 & 3);  // permuted V row for u=0 (u=1: +4)

  for (int tt = tbase + w; tt < tend; tt += 4) {
    const int t0 = tt * 32;
    int tA = t0 + l15;      if (tA > 2099) tA = 2099;
    int tB = t0 + 16 + l15; if (tB > 2099) tB = 2099;
    const u16* rowA = (tA < 75) ? uncls + ((size_t)b * 75 + tA) * 256
                                : nxp + ((size_t)b * 2025 + (tA - 75)) * 256;
    const u16* rowB = (tB < 75) ? uncls + ((size_t)b * 75 + tB) * 256
                                : nxp + ((size_t)b * 2025 + (tB - 75)) * 256;

    // ---- project K,V: C[d][token], 8 ksteps over 256 ch ----
    f32x4 aK[2][2] = {}, aV[2][2] = {};
    __builtin_amdgcn_s_setprio(1);
#pragma unroll
    for (int ks = 0; ks < 8; ks++) {
      bf16x8 nA = __builtin_bit_cast(bf16x8, *(const s16x8*)(rowA + ks * 32 + g * 8));
      bf16x8 nB = __builtin_bit_cast(bf16x8, *(const s16x8*)(rowB + ks * 32 + g * 8));
      const int cb = (ks * 64 + g * 16) ^ xw;
      bf16x8 k0 = __builtin_bit_cast(bf16x8, *(const s16x8*)(WL + l15 * 256 + (cb >> 1)));
      bf16x8 k1 = __builtin_bit_cast(bf16x8, *(const s16x8*)(WL + (16 + l15) * 256 + (cb >> 1)));
      bf16x8 w0 = __builtin_bit_cast(bf16x8, *(const s16x8*)(WL + (32 + l15) * 256 + (cb >> 1)));
      bf16x8 w1 = __builtin_bit_cast(bf16x8, *(const s16x8*)(WL + (48 + l15) * 256 + (cb >> 1)));
      aK[0][0] = mfma16(k0, nA, aK[0][0]);
      aK[0][1] = mfma16(k0, nB, aK[0][1]);
      aK[1][0] = mfma16(k1, nA, aK[1][0]);
      aK[1][1] = mfma16(k1, nB, aK[1][1]);
      aV[0][0] = mfma16(w0, nA, aV[0][0]);
      aV[0][1] = mfma16(w0, nB, aV[0][1]);
      aV[1][0] = mfma16(w1, nA, aV[1][0]);
      aV[1][1] = mfma16(w1, nB, aV[1][1]);
    }
    __builtin_amdgcn_s_setprio(0);

    // ---- K fragments fully in-register (k-slot 8g+e holds d = pi(8g+e)) ----
    uint4 kwA, kwB;
    kwA.x = pkbf(aK[0][0][0] + bk[0][0], aK[0][0][1] + bk[0][1]);
    kwA.y = pkbf(aK[0][0][2] + bk[0][2], aK[0][0][3] + bk[0][3]);
    kwA.z = pkbf(aK[1][0][0] + bk[1][0], aK[1][0][1] + bk[1][1]);
    kwA.w = pkbf(aK[1][0][2] + bk[1][2], aK[1][0][3] + bk[1][3]);
    kwB.x = pkbf(aK[0][1][0] + bk[0][0], aK[0][1][1] + bk[0][1]);
    kwB.y = pkbf(aK[0][1][2] + bk[0][2], aK[0][1][3] + bk[0][3]);
    kwB.z = pkbf(aK[1][1][0] + bk[1][0], aK[1][1][1] + bk[1][1]);
    kwB.w = pkbf(aK[1][1][2] + bk[1][2], aK[1][1][3] + bk[1][3]);
    bf16x8 bA = __builtin_bit_cast(bf16x8, kwA);
    bf16x8 bB = __builtin_bit_cast(bf16x8, kwB);

    // ---- V pack to LDS at PERMUTED row positions (b64 writes) ----
#pragma unroll
    for (int s2 = 0; s2 < 2; s2++) {
      uint2 pv0, pv1;
      pv0.x = pkbf(aV[s2][0][0] + bvb[s2][0], aV[s2][0][1] + bvb[s2][1]);
      pv0.y = pkbf(aV[s2][0][2] + bvb[s2][2], aV[s2][0][3] + bvb[s2][3]);
      pv1.x = pkbf(aV[s2][1][0] + bvb[s2][0], aV[s2][1][1] + bvb[s2][1]);
      pv1.y = pkbf(aV[s2][1][2] + bvb[s2][2], aV[s2][1][3] + bvb[s2][3]);
      *(uint2*)&VL[srowA * 36 + s2 * 16 + 4 * g] = pv0;
      *(uint2*)&VL[(srowA + 4) * 36 + s2 * 16 + 4 * g] = pv1;
    }

    // ---- V fragments (B-operand: rows = permuted token slots) ----
    s16x8 v0, v1;
#pragma unroll
    for (int e = 0; e < 8; e++) {
      v0[e] = (short)VL[(8 * g + e) * 36 + l15];
      v1[e] = (short)VL[(8 * g + e) * 36 + 16 + l15];
    }
    bf16x8 bv0 = __builtin_bit_cast(bf16x8, v0);
    bf16x8 bv1 = __builtin_bit_cast(bf16x8, v1);

    const bool lastTile = (t0 == 2080);

#pragma unroll
    for (int qt = 0; qt < 5; qt++) {
      f32x4 z = {0.f, 0.f, 0.f, 0.f};
      f32x4 sA = mfma16(bA, bq[qt], z);
      f32x4 sB = mfma16(bB, bq[qt], z);
      if (lastTile && g >= 1) {   // tokens t0+16+4g+r >= 2100
        sB[0] = sB[1] = sB[2] = sB[3] = -1e30f;
      }
      f32x4 pA, pB;
#pragma unroll
      for (int r = 0; r < 4; r++) {
        pA[r] = exp2f(sA[r]);
        pB[r] = exp2f(sB[r]);
      }
      llc[qt] += pA[0] + pA[1] + pA[2] + pA[3] + pB[0] + pB[1] + pB[2] + pB[3];
      // P fragment fully in-register (k-slot 8g+e holds token pi(8g+e))
      uint4 pw;
      pw.x = pkbf(pA[0], pA[1]);
      pw.y = pkbf(pA[2], pA[3]);
      pw.z = pkbf(pB[0], pB[1]);
      pw.w = pkbf(pB[2], pB[3]);
      bf16x8 bp = __builtin_bit_cast(bf16x8, pw);
      acc[qt][0] = mfma16(bp, bv0, acc[qt][0]);
      acc[qt][1] = mfma16(bp, bv1, acc[qt][1]);
    }
  }

  // ---- one-time denominator reduce; combine 4 wave-partials ----
#pragma unroll
  for (int qt = 0; qt < 5; qt++) {
    float t = llc[qt];
    t += __shfl_xor(t, 16, 64);
    t += __shfl_xor(t, 32, 64);
    llc[qt] = t;
  }
  __syncthreads();   // everyone done with WL/VL
  float* MC = (float*)arena;   // [4][2560]
#pragma unroll
  for (int qt = 0; qt < 5; qt++)
#pragma unroll
    for (int dh = 0; dh < 2; dh++)
#pragma unroll
      for (int r = 0; r < 4; r++) {
        int q = qt * 16 + 4 * g + r;
        MC[w * 2560 + q * 32 + dh * 16 + l15] = acc[qt][dh][r];
      }
  if (lane < 16) {
#pragma unroll
    for (int qt = 0; qt < 5; qt++) mlS[w][qt * 16 + l15] = llc[qt];
  }
  __syncthreads();

  if (tid < 75) {
    float L = mlS[0][tid] + mlS[1][tid] + mlS[2][tid] + mlS[3][tid];
    pml[(size_t)bid * 80 + tid] = L;
  }
  for (int idx = tid; idx < 2400; idx += 256) {
    int q = idx >> 5;
    float O = MC[q * 32 + (idx & 31)] + MC[2560 + q * 32 + (idx & 31)] +
              MC[5120 + q * 32 + (idx & 31)] + MC[7680 + q * 32 + (idx & 31)];
    pO[(size_t)bid * 2400 + idx] = O;
  }
}

// ---------------- combine the two token-halves ----------------
__global__ __launch_bounds__(256) void k_acomb(const float* __restrict__ pO,
                                               const float* __restrict__ pml,
                                               u16* __restrict__ obf) {
  const int bid = blockIdx.x;  // 0..511 = (b,h)
  const int b = bid & 63, h = bid >> 6;
  const int tid = threadIdx.x;
  for (int idx = tid; idx < 2400; idx += 256) {
    int q = idx >> 5, d = idx & 31;
    float L = pml[(size_t)bid * 80 + q] + pml[(size_t)(bid + 512) * 80 + q];
    float O = pO[(size_t)bid * 2400 + idx] + pO[(size_t)(bid + 512) * 2400 + idx];
    obf[(size_t)(b * 75 + q) * 256 + h * 32 + d] = f2bf(O / L);
  }
}

// ---------------- host ----------------
extern "C" void kernel_launch(void* const* d_in, const int* in_sizes, int n_in,
                              void* d_out, int out_size, void* d_ws, size_t ws_size,
                              hipStream_t stream) {
  const float* x_cls   = (const float*)d_in[0];
  const float* x_patch = (const float*)d_in[1];
  const float* ln1_w   = (const float*)d_in[2];
  const float* ln1_b   = (const float*)d_in[3];
  const float* q_w     = (const float*)d_in[4];
  const float* k_w     = (const float*)d_in[5];
  const float* v_w     = (const float*)d_in[6];
  const float* proj_w  = (const float*)d_in[7];
  const float* proj_b  = (const float*)d_in[8];
  const float* ln2_w   = (const float*)d_in[9];
  const float* ln2_b   = (const float*)d_in[10];
  const float* fc1_w   = (const float*)d_in[11];
  const float* fc1_b   = (const float*)d_in[12];
  const float* fc2_w   = (const float*)d_in[13];
  const float* fc2_b   = (const float*)d_in[14];
  const float* gamma1  = (const float*)d_in[15];
  const float* gamma2  = (const float*)d_in[16];
  float* xc = (float*)d_out;

  char* ws = (char*)d_ws;
  size_t off = 0;
  auto alloc = [&](size_t bytes) {
    char* p = ws + off;
    off += (bytes + 255) & ~(size_t)255;
    return p;
  };
  u16* nxp   = (u16*)alloc(129600ull * 256 * 2);
  u16* uncls = (u16*)alloc(4800ull * 256 * 2);
  u16* qb    = (u16*)alloc(4800ull * 256 * 2);
  u16* ob    = (u16*)alloc(4800ull * 256 * 2);
  u16* xn    = (u16*)alloc(4800ull * 256 * 2);
  u16* hb    = (u16*)alloc(4800ull * 1024 * 2);
  u16* qp    = (u16*)alloc(2ull * 65536 * 2);
  u16* kvp   = (u16*)alloc(2ull * 131072 * 2);
  u16* pjp   = (u16*)alloc(2ull * 65536 * 2);
  u16* f1p   = (u16*)alloc(2ull * 262144 * 2);
  u16* f2p   = (u16*)alloc(2ull * 262144 * 2);
  float* bias_kv = (float*)alloc(2ull * 512 * 4);
  float* bias_q  = (float*)alloc(2ull * 256 * 4);
  float* bias_f1 = (float*)alloc(2ull * 1024 * 4);
  float* pO  = (float*)alloc(1024ull * 2400 * 4);
  float* pml = (float*)alloc(1024ull * 80 * 4);

  k_prep<<<35136, 256, 0, stream>>>(x_cls, x_patch, k_w, v_w, q_w, proj_w, fc1_w, fc2_w,
                                    ln1_w, ln1_b, ln2_w, ln2_b, fc1_b,
                                    kvp, qp, pjp, f1p, f2p,
                                    bias_kv, bias_q, bias_f1, xc, nxp);

  const float qscale = 0.25503489f;  // 1/sqrt(32) * log2(e)
  for (int i = 0; i < 2; i++) {
    k_norm<<<1200, 256, 0, stream>>>(xc, uncls, 4800);
    k_gemm6<<<150, 256, 0, stream>>>(uncls, qp + i * 65536, 256, 256, 1, 1, qscale,
                                     bias_q + i * 256, nullptr, qb, nullptr);
    k_fattn<<<1024, 256, 0, stream>>>(qb, uncls, nxp, kvp + i * 131072,
                                      bias_kv + i * 512, pO, pml);
    k_acomb<<<512, 256, 0, stream>>>(pO, pml, ob);
    k_gemm6<<<150, 256, 0, stream>>>(ob, pjp + i * 65536, 256, 256, 2, 1, 0.f,
                                     proj_b + i * 256, gamma1 + i * 256, nullptr, xc);
    k_norm<<<1200, 256, 0, stream>>>(xc, xn, 4800);
    k_gemm6<<<600, 256, 0, stream>>>(xn, f1p + i * 262144, 1024, 256, 3, 3, 0.f,
                                     bias_f1 + i * 1024, nullptr, hb, nullptr);
    k_gemm6<<<150, 256, 0, stream>>>(hb, f2p + i * 262144, 256, 1024, 2, 1, 0.f,
                                     fc2_b + i * 256, gamma2 + i * 256, nullptr, xc);
  }
}

// Round 16
// 329.326 us; speedup vs baseline: 1.0930x; 1.0071x over previous
//
#include <hip/hip_runtime.h>
#include <cstdint>
#include <cstddef>

typedef unsigned short u16;
typedef float f32x4 __attribute__((ext_vector_type(4)));
typedef short s16x8 __attribute__((ext_vector_type(8)));
typedef unsigned short u16x4 __attribute__((ext_vector_type(4)));
typedef __bf16 bf16x8 __attribute__((ext_vector_type(8)));

#define DEV static __device__ __forceinline__

DEV u16 f2bf(float f) {
  uint32_t x = __float_as_uint(f);
  return (u16)((x + 0x7fffu + ((x >> 16) & 1u)) >> 16);  // RNE
}

DEV f32x4 mfma16(bf16x8 a, bf16x8 b, f32x4 c) {
  return __builtin_amdgcn_mfma_f32_16x16x32_bf16(a, b, c, 0, 0, 0);
}

DEV void mfma_bf16_asm(f32x4& acc, s16x8 a, s16x8 b) {
  asm volatile("v_mfma_f32_16x16x32_bf16 %0, %1, %2, %0" : "+v"(acc) : "v"(a), "v"(b));
}

DEV uint32_t pkbf(float lo, float hi) {
  uint32_t r;
  asm("v_cvt_pk_bf16_f32 %0, %1, %2" : "=v"(r) : "v"(lo), "v"(hi));
  return r;
}

// ---------------- mega prep: folds + casts + x_cls copy + patch norm ----------------
__global__ __launch_bounds__(256) void k_prep(
    const float* __restrict__ x_cls, const float* __restrict__ x_patch,
    const float* __restrict__ k_w, const float* __restrict__ v_w,
    const float* __restrict__ q_w, const float* __restrict__ proj_w,
    const float* __restrict__ fc1_w, const float* __restrict__ fc2_w,
    const float* __restrict__ ln1_w, const float* __restrict__ ln1_b,
    const float* __restrict__ ln2_w, const float* __restrict__ ln2_b,
    const float* __restrict__ fc1_b,
    u16* __restrict__ kvp, u16* __restrict__ qp, u16* __restrict__ pjp,
    u16* __restrict__ f1p, u16* __restrict__ f2p,
    float* __restrict__ bias_kv, float* __restrict__ bias_q, float* __restrict__ bias_f1,
    float* __restrict__ xc, u16* __restrict__ nxp) {
  const int jb = blockIdx.x;
  const int lane = threadIdx.x & 63;
  if (jb >= 2736) {
    int wv = (jb - 2736) * 4 + (threadIdx.x >> 6);
    if (wv >= 129600) return;
    float4 v = ((const float4*)(x_patch + (size_t)wv * 256))[lane];
    float s = v.x + v.y + v.z + v.w;
    float q = v.x * v.x + v.y * v.y + v.z * v.z + v.w * v.w;
#pragma unroll
    for (int m = 1; m < 64; m <<= 1) {
      s += __shfl_xor(s, m, 64);
      q += __shfl_xor(q, m, 64);
    }
    float mean = s * (1.f / 256.f);
    float var = q * (1.f / 256.f) - mean * mean;
    float rstd = rsqrtf(var + 1e-5f);
    u16x4 o;
    o[0] = f2bf((v.x - mean) * rstd);
    o[1] = f2bf((v.y - mean) * rstd);
    o[2] = f2bf((v.z - mean) * rstd);
    o[3] = f2bf((v.w - mean) * rstd);
    ((u16x4*)(nxp + (size_t)wv * 256))[lane] = o;
    return;
  }
  if (jb >= 1536) {
    int i = (jb - 1536) * 256 + threadIdx.x;
    ((float4*)xc)[i] = ((const float4*)x_cls)[i];
    return;
  }
  const int layer = jb >= 768 ? 1 : 0;
  const int j = jb - layer * 768;
  const float* W;
  const float* lw = ln1_w + layer * 256;
  const float* lb = ln1_b + layer * 256;
  const float* b0 = nullptr;
  u16* Wout;
  float* bout = nullptr;
  int rowoff;
  if (j < 64)       { W = k_w + layer * 65536;    Wout = kvp + layer * 131072;         bout = bias_kv + layer * 512;       rowoff = j * 4; }
  else if (j < 128) { W = v_w + layer * 65536;    Wout = kvp + layer * 131072 + 65536; bout = bias_kv + layer * 512 + 256; rowoff = (j - 64) * 4; }
  else if (j < 192) { W = q_w + layer * 65536;    Wout = qp + layer * 65536;           bout = bias_q + layer * 256;        rowoff = (j - 128) * 4; }
  else if (j < 448) { W = fc1_w + layer * 262144; lw = ln2_w + layer * 256; lb = ln2_b + layer * 256; b0 = fc1_b + layer * 1024;
                      Wout = f1p + layer * 262144; bout = bias_f1 + layer * 1024;      rowoff = (j - 192) * 4; }
  else if (j < 512) { W = proj_w + layer * 65536; lw = nullptr;                        Wout = pjp + layer * 65536;         rowoff = (j - 448) * 4; }
  else              { W = fc2_w + layer * 262144; lw = nullptr;                        Wout = f2p + layer * 262144;        rowoff = (j - 512) * 4; }
  const int wv = rowoff + (threadIdx.x >> 6);
  float4 w4 = ((const float4*)(W + (size_t)wv * 256))[lane];
  u16x4 o;
  if (lw) {
    float4 s4 = ((const float4*)lw)[lane];
    o[0] = f2bf(w4.x * s4.x); o[1] = f2bf(w4.y * s4.y);
    o[2] = f2bf(w4.z * s4.z); o[3] = f2bf(w4.w * s4.w);
  } else {
    o[0] = f2bf(w4.x); o[1] = f2bf(w4.y); o[2] = f2bf(w4.z); o[3] = f2bf(w4.w);
  }
  ((u16x4*)(Wout + (size_t)wv * 256))[lane] = o;
  if (bout) {
    float4 t4 = ((const float4*)lb)[lane];
    float d = w4.x * t4.x + w4.y * t4.y + w4.z * t4.z + w4.w * t4.w;
#pragma unroll
    for (int m = 1; m < 64; m <<= 1) d += __shfl_xor(d, m, 64);
    if (lane == 0) bout[wv] = (b0 ? b0[wv] : 0.f) + d;
  }
}

// ---------------- Pure normalize (affine folded into weights) ----------
__global__ __launch_bounds__(256) void k_norm(const float* __restrict__ src,
                                              u16* __restrict__ out, int ntok) {
  int wv = blockIdx.x * 4 + (threadIdx.x >> 6), lane = threadIdx.x & 63;
  if (wv >= ntok) return;
  float4 v = ((const float4*)(src + (size_t)wv * 256))[lane];
  float s = v.x + v.y + v.z + v.w;
  float q = v.x * v.x + v.y * v.y + v.z * v.z + v.w * v.w;
#pragma unroll
  for (int m = 1; m < 64; m <<= 1) {
    s += __shfl_xor(s, m, 64);
    q += __shfl_xor(q, m, 64);
  }
  float mean = s * (1.f / 256.f);
  float var = q * (1.f / 256.f) - mean * mean;
  float rstd = rsqrtf(var + 1e-5f);
  u16x4 o;
  o[0] = f2bf((v.x - mean) * rstd);
  o[1] = f2bf((v.y - mean) * rstd);
  o[2] = f2bf((v.z - mean) * rstd);
  o[3] = f2bf((v.w - mean) * rstd);
  ((u16x4*)(out + (size_t)wv * 256))[lane] = o;
}

// ---------------- small-M MFMA GEMM: 64x128 tile, BK=64 (R8-proven) ----------------
// modes: 1 = q store: bf16(v*scale) with PERMUTED head channel (slot = pi^-1(dd))
//        2 = of32[m*N+n] += gamma[n]*v; 3 = bf16(gelu(v))
__global__ __launch_bounds__(256) void k_gemm6(const u16* __restrict__ A,
                                               const u16* __restrict__ Bw,
                                               int N, int K, int mode,
                                               int lognby, float scale,
                                               const float* __restrict__ bias,
                                               const float* __restrict__ gamma,
                                               u16* __restrict__ obf,
                                               float* __restrict__ of32) {
  __shared__ __align__(16) char smA[8192];
  __shared__ __align__(16) char smB[16384];
  const int tid = threadIdx.x, lane = tid & 63, wid = tid >> 6;
  const int wm = wid >> 1, wn = wid & 1;
  const int bid = blockIdx.x;
  const int by = bid & ((1 << lognby) - 1), bx = bid >> lognby;
  const int m0 = bx * 64, n0 = by * 128;
  const int g = lane >> 4, l15 = lane & 15;

  f32x4 acc[2][4] = {};

  for (int k0 = 0; k0 < K; k0 += 64) {
#pragma unroll
    for (int c = 0; c < 2; c++) {
      int ee = tid + 256 * c;
      int row = ee >> 3, sl = ee & 7;
      s16x8 av = *(const s16x8*)(A + (size_t)(m0 + row) * K + k0 + sl * 8);
      *(s16x8*)(smA + row * 128 + ((sl * 16) ^ ((row & 7) << 4))) = av;
    }
#pragma unroll
    for (int c = 0; c < 4; c++) {
      int ee = tid + 256 * c;
      int row = ee >> 3, sl = ee & 7;
      s16x8 bv = *(const s16x8*)(Bw + (size_t)(n0 + row) * K + k0 + sl * 8);
      *(s16x8*)(smB + row * 128 + ((sl * 16) ^ ((row & 7) << 4))) = bv;
    }
    __syncthreads();
    s16x8 af[2][2], bfr[4][2];
#pragma unroll
    for (int s = 0; s < 2; s++) {
#pragma unroll
      for (int i = 0; i < 2; i++) {
        int r = wm * 32 + i * 16 + l15;
        af[i][s] = *(const s16x8*)(smA + r * 128 + (((s * 4 + g) * 16) ^ ((r & 7) << 4)));
      }
#pragma unroll
      for (int jj = 0; jj < 4; jj++) {
        int n = wn * 64 + jj * 16 + l15;
        bfr[jj][s] = *(const s16x8*)(smB + n * 128 + (((s * 4 + g) * 16) ^ ((n & 7) << 4)));
      }
    }
#pragma unroll
    for (int s = 0; s < 2; s++)
#pragma unroll
      for (int i = 0; i < 2; i++)
#pragma unroll
        for (int jj = 0; jj < 4; jj++)
          mfma_bf16_asm(acc[i][jj], af[i][s], bfr[jj][s]);
    __syncthreads();
  }
  asm volatile("s_nop 7\n\ts_nop 7" ::: "memory");

#pragma unroll
  for (int i = 0; i < 2; i++) {
#pragma unroll
    for (int jj = 0; jj < 4; jj++) {
      int gmBase = m0 + wm * 32 + i * 16 + g * 4;
      int gn = n0 + wn * 64 + jj * 16 + l15;
      float bs = bias[gn];
#pragma unroll
      for (int r = 0; r < 4; r++) {
        int gm = gmBase + r;
        float v = acc[i][jj][r] + bs;
        if (mode == 1) {
          // permute channel within head so attention's k-slot reads are linear:
          // slot(dd) = 8*((dd&15)>>2) + 4*(dd>>4) + (dd&3)
          int hd = gn & 31;
          int slot = 8 * ((hd & 15) >> 2) + 4 * (hd >> 4) + (hd & 3);
          obf[(size_t)gm * N + (gn & ~31) + slot] = f2bf(v * scale);
        } else if (mode == 2) {
          of32[(size_t)gm * N + gn] += gamma[gn] * v;
        } else {
          obf[(size_t)gm * N + gn] = f2bf(0.5f * v * (1.f + erff(v * 0.70710678118654752f)));
        }
      }
    }
  }
}

// ---------------- Fused K/V-projection + flash attention, token-split x2 ----------------
// R11 body (in-register K/P via k-dim permutation) at 2 blocks/CU (R14-proven best).
__global__ __launch_bounds__(256, 2) void k_fattn(const u16* __restrict__ qb,
                                                  const u16* __restrict__ uncls,
                                                  const u16* __restrict__ nxp,
                                                  const u16* __restrict__ wkv,
                                                  const float* __restrict__ bias_kv,
                                                  float* __restrict__ pO,
                                                  float* __restrict__ pml) {
  __shared__ __align__(16) char arena[54784];   // WL 32768 + 4xVL 2304 + PAD (caps 2 blk/CU)
  __shared__ float mlS[4][80];
  const int bid = blockIdx.x;
  const int b = bid & 63, h = (bid >> 6) & 7, half = bid >> 9;
  const int tid = threadIdx.x, lane = tid & 63, w = tid >> 6;
  const int l15 = lane & 15, g = lane >> 4;
  const int tbase = half * 33, tend = tbase + 33;

  u16* WL = (u16*)arena;                        // [64][256] u16, row-xor swizzle
  u16* VL = (u16*)(arena + 32768 + w * 2304);   // [32 slot][36 d] u16 (padded rows)

  // ---- stage head weights (Wk rows 0..31, Wv rows 32..63) ----
  for (int it = tid; it < 2048; it += 256) {
    int row = it >> 5, c16 = it & 31;
    int srcRow = (row < 32) ? (h * 32 + row) : (256 + h * 32 + (row - 32));
    s16x8 w8 = *(const s16x8*)(wkv + (size_t)srcRow * 256 + c16 * 8);
    *(s16x8*)(WL + row * 256 + (((c16 * 16) ^ ((row & 7) << 4)) >> 1)) = w8;
  }

  float bk[2][4], bvb[2][4];
#pragma unroll
  for (int s2 = 0; s2 < 2; s2++)
#pragma unroll
    for (int r = 0; r < 4; r++) {
      bk[s2][r] = bias_kv[h * 32 + s2 * 16 + 4 * g + r];
      bvb[s2][r] = bias_kv[256 + h * 32 + s2 * 16 + 4 * g + r];
    }

  bf16x8 bq[5];
#pragma unroll
  for (int qt = 0; qt < 5; qt++) {
    int q = qt * 16 + l15; if (q > 74) q = 74;
    s16x8 qv = *(const s16x8*)(qb + (size_t)(b * 75 + q) * 256 + h * 32 + g * 8);
    bq[qt] = __builtin_bit_cast(bf16x8, qv);
  }

  f32x4 acc[5][2] = {};
  float llc[5];
#pragma unroll
  for (int qt = 0; qt < 5; qt++) llc[qt] = 0.f;

  __syncthreads();  // weights staged

  const int xw = (l15 & 7) << 4;                 // weight-row xor
  const int srowA = 8 * (l15 >> 2) + (l15 & 3);  // permuted V row for u=0 (u=1: +4)

  for (int tt = tbase + w; tt < tend; tt += 4) {
    const int t0 = tt * 32;
    int tA = t0 + l15;      if (tA > 2099) tA = 2099;
    int tB = t0 + 16 + l15; if (tB > 2099) tB = 2099;
    const u16* rowA = (tA < 75) ? uncls + ((size_t)b * 75 + tA) * 256
                                : nxp + ((size_t)b * 2025 + (tA - 75)) * 256;
    const u16* rowB = (tB < 75) ? uncls + ((size_t)b * 75 + tB) * 256
                                : nxp + ((size_t)b * 2025 + (tB - 75)) * 256;

    // ---- project K,V: C[d][token], 8 ksteps over 256 ch ----
    f32x4 aK[2][2] = {}, aV[2][2] = {};
    __builtin_amdgcn_s_setprio(1);
#pragma unroll
    for (int ks = 0; ks < 8; ks++) {
      bf16x8 nA = __builtin_bit_cast(bf16x8, *(const s16x8*)(rowA + ks * 32 + g * 8));
      bf16x8 nB = __builtin_bit_cast(bf16x8, *(const s16x8*)(rowB + ks * 32 + g * 8));
      const int cb = (ks * 64 + g * 16) ^ xw;
      bf16x8 k0 = __builtin_bit_cast(bf16x8, *(const s16x8*)(WL + l15 * 256 + (cb >> 1)));
      bf16x8 k1 = __builtin_bit_cast(bf16x8, *(const s16x8*)(WL + (16 + l15) * 256 + (cb >> 1)));
      bf16x8 w0 = __builtin_bit_cast(bf16x8, *(const s16x8*)(WL + (32 + l15) * 256 + (cb >> 1)));
      bf16x8 w1 = __builtin_bit_cast(bf16x8, *(const s16x8*)(WL + (48 + l15) * 256 + (cb >> 1)));
      aK[0][0] = mfma16(k0, nA, aK[0][0]);
      aK[0][1] = mfma16(k0, nB, aK[0][1]);
      aK[1][0] = mfma16(k1, nA, aK[1][0]);
      aK[1][1] = mfma16(k1, nB, aK[1][1]);
      aV[0][0] = mfma16(w0, nA, aV[0][0]);
      aV[0][1] = mfma16(w0, nB, aV[0][1]);
      aV[1][0] = mfma16(w1, nA, aV[1][0]);
      aV[1][1] = mfma16(w1, nB, aV[1][1]);
    }
    __builtin_amdgcn_s_setprio(0);

    // ---- K fragments fully in-register (k-slot 8g+e holds d = pi(8g+e)) ----
    uint4 kwA, kwB;
    kwA.x = pkbf(aK[0][0][0] + bk[0][0], aK[0][0][1] + bk[0][1]);
    kwA.y = pkbf(aK[0][0][2] + bk[0][2], aK[0][0][3] + bk[0][3]);
    kwA.z = pkbf(aK[1][0][0] + bk[1][0], aK[1][0][1] + bk[1][1]);
    kwA.w = pkbf(aK[1][0][2] + bk[1][2], aK[1][0][3] + bk[1][3]);
    kwB.x = pkbf(aK[0][1][0] + bk[0][0], aK[0][1][1] + bk[0][1]);
    kwB.y = pkbf(aK[0][1][2] + bk[0][2], aK[0][1][3] + bk[0][3]);
    kwB.z = pkbf(aK[1][1][0] + bk[1][0], aK[1][1][1] + bk[1][1]);
    kwB.w = pkbf(aK[1][1][2] + bk[1][2], aK[1][1][3] + bk[1][3]);
    bf16x8 bA = __builtin_bit_cast(bf16x8, kwA);
    bf16x8 bB = __builtin_bit_cast(bf16x8, kwB);

    // ---- V pack to LDS at PERMUTED row positions (b64 writes) ----
#pragma unroll
    for (int s2 = 0; s2 < 2; s2++) {
      uint2 pv0, pv1;
      pv0.x = pkbf(aV[s2][0][0] + bvb[s2][0], aV[s2][0][1] + bvb[s2][1]);
      pv0.y = pkbf(aV[s2][0][2] + bvb[s2][2], aV[s2][0][3] + bvb[s2][3]);
      pv1.x = pkbf(aV[s2][1][0] + bvb[s2][0], aV[s2][1][1] + bvb[s2][1]);
      pv1.y = pkbf(aV[s2][1][2] + bvb[s2][2], aV[s2][1][3] + bvb[s2][3]);
      *(uint2*)&VL[srowA * 36 + s2 * 16 + 4 * g] = pv0;
      *(uint2*)&VL[(srowA + 4) * 36 + s2 * 16 + 4 * g] = pv1;
    }

    // ---- V fragments (B-operand: rows = permuted token slots) ----
    s16x8 v0, v1;
#pragma unroll
    for (int e = 0; e < 8; e++) {
      v0[e] = (short)VL[(8 * g + e) * 36 + l15];
      v1[e] = (short)VL[(8 * g + e) * 36 + 16 + l15];
    }
    bf16x8 bv0 = __builtin_bit_cast(bf16x8, v0);
    bf16x8 bv1 = __builtin_bit_cast(bf16x8, v1);

    const bool lastTile = (t0 == 2080);

#pragma unroll
    for (int qt = 0; qt < 5; qt++) {
      f32x4 z = {0.f, 0.f, 0.f, 0.f};
      f32x4 sA = mfma16(bA, bq[qt], z);
      f32x4 sB = mfma16(bB, bq[qt], z);
      if (lastTile && g >= 1) {   // tokens t0+16+4g+r >= 2100
        sB[0] = sB[1] = sB[2] = sB[3] = -1e30f;
      }
      f32x4 pA, pB;
#pragma unroll
      for (int r = 0; r < 4; r++) {
        pA[r] = exp2f(sA[r]);
        pB[r] = exp2f(sB[r]);
      }
      llc[qt] += pA[0] + pA[1] + pA[2] + pA[3] + pB[0] + pB[1] + pB[2] + pB[3];
      // P fragment fully in-register (k-slot 8g+e holds token pi(8g+e))
      uint4 pw;
      pw.x = pkbf(pA[0], pA[1]);
      pw.y = pkbf(pA[2], pA[3]);
      pw.z = pkbf(pB[0], pB[1]);
      pw.w = pkbf(pB[2], pB[3]);
      bf16x8 bp = __builtin_bit_cast(bf16x8, pw);
      acc[qt][0] = mfma16(bp, bv0, acc[qt][0]);
      acc[qt][1] = mfma16(bp, bv1, acc[qt][1]);
    }
  }

  // ---- one-time denominator reduce; combine 4 wave-partials ----
#pragma unroll
  for (int qt = 0; qt < 5; qt++) {
    float t = llc[qt];
    t += __shfl_xor(t, 16, 64);
    t += __shfl_xor(t, 32, 64);
    llc[qt] = t;
  }
  __syncthreads();   // everyone done with WL/VL
  float* MC = (float*)arena;   // [4][2560]
#pragma unroll
  for (int qt = 0; qt < 5; qt++)
#pragma unroll
    for (int dh = 0; dh < 2; dh++)
#pragma unroll
      for (int r = 0; r < 4; r++) {
        int q = qt * 16 + 4 * g + r;
        MC[w * 2560 + q * 32 + dh * 16 + l15] = acc[qt][dh][r];
      }
  if (lane < 16) {
#pragma unroll
    for (int qt = 0; qt < 5; qt++) mlS[w][qt * 16 + l15] = llc[qt];
  }
  __syncthreads();

  if (tid < 75) {
    float L = mlS[0][tid] + mlS[1][tid] + mlS[2][tid] + mlS[3][tid];
    pml[(size_t)bid * 80 + tid] = L;
  }
  for (int idx = tid; idx < 2400; idx += 256) {
    int q = idx >> 5;
    float O = MC[q * 32 + (idx & 31)] + MC[2560 + q * 32 + (idx & 31)] +
              MC[5120 + q * 32 + (idx & 31)] + MC[7680 + q * 32 + (idx & 31)];
    pO[(size_t)bid * 2400 + idx] = O;
  }
}

// ---------------- combine the two token-halves ----------------
__global__ __launch_bounds__(256) void k_acomb(const float* __restrict__ pO,
                                               const float* __restrict__ pml,
                                               u16* __restrict__ obf) {
  const int bid = blockIdx.x;  // 0..511 = (b,h)
  const int b = bid & 63, h = bid >> 6;
  const int tid = threadIdx.x;
  for (int idx = tid; idx < 2400; idx += 256) {
    int q = idx >> 5, d = idx & 31;
    float L = pml[(size_t)bid * 80 + q] + pml[(size_t)(bid + 512) * 80 + q];
    float O = pO[(size_t)bid * 2400 + idx] + pO[(size_t)(bid + 512) * 2400 + idx];
    obf[(size_t)(b * 75 + q) * 256 + h * 32 + d] = f2bf(O / L);
  }
}

// ---------------- host ----------------
extern "C" void kernel_launch(void* const* d_in, const int* in_sizes, int n_in,
                              void* d_out, int out_size, void* d_ws, size_t ws_size,
                              hipStream_t stream) {
  const float* x_cls   = (const float*)d_in[0];
  const float* x_patch = (const float*)d_in[1];
  const float* ln1_w   = (const float*)d_in[2];
  const float* ln1_b   = (const float*)d_in[3];
  const float* q_w     = (const float*)d_in[4];
  const float* k_w     = (const float*)d_in[5];
  const float* v_w     = (const float*)d_in[6];
  const float* proj_w  = (const float*)d_in[7];
  const float* proj_b  = (const float*)d_in[8];
  const float* ln2_w   = (const float*)d_in[9];
  const float* ln2_b   = (const float*)d_in[10];
  const float* fc1_w   = (const float*)d_in[11];
  const float* fc1_b   = (const float*)d_in[12];
  const float* fc2_w   = (const float*)d_in[13];
  const float* fc2_b   = (const float*)d_in[14];
  const float* gamma1  = (const float*)d_in[15];
  const float* gamma2  = (const float*)d_in[16];
  float* xc = (float*)d_out;

  char* ws = (char*)d_ws;
  size_t off = 0;
  auto alloc = [&](size_t bytes) {
    char* p = ws + off;
    off += (bytes + 255) & ~(size_t)255;
    return p;
  };
  u16* nxp   = (u16*)alloc(129600ull * 256 * 2);
  u16* uncls = (u16*)alloc(4800ull * 256 * 2);
  u16* qb    = (u16*)alloc(4800ull * 256 * 2);
  u16* ob    = (u16*)alloc(4800ull * 256 * 2);
  u16* xn    = (u16*)alloc(4800ull * 256 * 2);
  u16* hb    = (u16*)alloc(4800ull * 1024 * 2);
  u16* qp    = (u16*)alloc(2ull * 65536 * 2);
  u16* kvp   = (u16*)alloc(2ull * 131072 * 2);
  u16* pjp   = (u16*)alloc(2ull * 65536 * 2);
  u16* f1p   = (u16*)alloc(2ull * 262144 * 2);
  u16* f2p   = (u16*)alloc(2ull * 262144 * 2);
  float* bias_kv = (float*)alloc(2ull * 512 * 4);
  float* bias_q  = (float*)alloc(2ull * 256 * 4);
  float* bias_f1 = (float*)alloc(2ull * 1024 * 4);
  float* pO  = (float*)alloc(1024ull * 2400 * 4);
  float* pml = (float*)alloc(1024ull * 80 * 4);

  k_prep<<<35136, 256, 0, stream>>>(x_cls, x_patch, k_w, v_w, q_w, proj_w, fc1_w, fc2_w,
                                    ln1_w, ln1_b, ln2_w, ln2_b, fc1_b,
                                    kvp, qp, pjp, f1p, f2p,
                                    bias_kv, bias_q, bias_f1, xc, nxp);

  const float qscale = 0.25503489f;  // 1/sqrt(32) * log2(e)
  for (int i = 0; i < 2; i++) {
    k_norm<<<1200, 256, 0, stream>>>(xc, uncls, 4800);
    k_gemm6<<<150, 256, 0, stream>>>(uncls, qp + i * 65536, 256, 256, 1, 1, qscale,
                                     bias_q + i * 256, nullptr, qb, nullptr);
    k_fattn<<<1024, 256, 0, stream>>>(qb, uncls, nxp, kvp + i * 131072,
                                      bias_kv + i * 512, pO, pml);
    k_acomb<<<512, 256, 0, stream>>>(pO, pml, ob);
    k_gemm6<<<150, 256, 0, stream>>>(ob, pjp + i * 65536, 256, 256, 2, 1, 0.f,
                                     proj_b + i * 256, gamma1 + i * 256, nullptr, xc);
    k_norm<<<1200, 256, 0, stream>>>(xc, xn, 4800);
    k_gemm6<<<600, 256, 0, stream>>>(xn, f1p + i * 262144, 1024, 256, 3, 3, 0.f,
                                     bias_f1 + i * 1024, nullptr, hb, nullptr);
    k_gemm6<<<150, 256, 0, stream>>>(hb, f2p + i * 262144, 256, 1024, 2, 1, 0.f,
                                     fc2_b + i * 256, gamma2 + i * 256, nullptr, xc);
  }
}